// Round 4
// baseline (21523.767 us; speedup 1.0000x reference)
//
#include <hip/hip_runtime.h>
#include <stdint.h>

// Binary-weight MLP forward, exact int8 digit-plane formulation.
// R7: arithmetic-intensity fix. Evidence from R3-R6: every schedule hits an
// effective L2->CU streaming rate of ~21-25 B/cyc regardless of pipelining
// depth => L2-bandwidth-bound, not LDS/latency. Remedy: one 1024-thread
// block per CU, MT=128 x NT=256 x KT=64, wave-tile 32x64 (acc unchanged at
// 128 AGPR). Same 48 KB of L2 traffic per CU-stage now feeds 256 wave-MFMAs
// (2340 cyc) instead of 128 => required L2 rate drops to ~21 B/cyc = the
// measured effective rate. All operands via global_load_lds (no wave
// duplication), 3-deep buffers (144 KB LDS), constant s_waitcnt vmcnt(3),
// one barrier per stage. Bijective XCD swizzle: each XCD owns 16 mb rows,
// so the 2 MB A-window is L2-resident and HBM-fetched once.

typedef int v4i  __attribute__((ext_vector_type(4)));
typedef int v16i __attribute__((ext_vector_type(16)));

#define B_ROWS   16384
#define DIM      4096
#define MT       128     // block m-tile (R7)
#define NT       256     // block n-tile (R7)
#define KT       64      // k-tile (pipeline stage)

#define WS_LOGIT  0
#define WS_W2S    65536
#define WS_B      69632
#define WS_A      (69632 + 16777216)
#define WS_NEEDED ((size_t)WS_A + 268435456ULL)

__device__ __forceinline__ void dma16(const void* g, void* l) {
    __builtin_amdgcn_global_load_lds(
        (const __attribute__((address_space(1))) void*)g,
        (__attribute__((address_space(3))) void*)l, 16, 0, 0);
}

// ---------------- pack x -> fragment-ordered digit planes in wsA -----------
// Global layout: offA(m,k,d) = (m>>5)<<19 | (k>>5)<<12 | d<<10 | L<<4 | (k&15)
//   with L = ((k>>4)&1)*32 + (m&31)  (== MFMA A-operand lane index).
__global__ void pack_x_frag_kernel(const float* __restrict__ x, int8_t* __restrict__ wsA) {
    __shared__ __align__(16) int8_t tile[16384];
    const int mb32 = blockIdx.x, t = threadIdx.x;
    const int r = t >> 3;          // row within 32-row group
    const int c = t & 7;           // float4-column subgroup
    const int kh = (c >> 2) & 1;   // (k>>4)&1 for this thread's elements
    const int L = kh * 32 + r;
    const int ldsQ = L * 16 + (c & 3) * 4;   // + i*4096 + d*1024
    const float* srcRow = x + ((size_t)(mb32 * 32 + r) << 12);
    int8_t* dstBase = wsA + ((size_t)mb32 << 19);

    for (int kw = 0; kw < 32; ++kw) {
#pragma unroll
        for (int i = 0; i < 4; ++i) {
            const int j = c + 8 * i;                       // float4 index in window
            float4 f = ((const float4*)(srcRow + (kw << 7)))[j];
            float fv[4] = {f.x, f.y, f.z, f.w};
            int dig[4][4];                                  // [elem][digit]
#pragma unroll
            for (int e = 0; e < 4; ++e) {
                int v = __float2int_rn(fv[e] * 67108864.0f); // * 2^26, exact
#pragma unroll
                for (int d = 0; d < 4; ++d) {
                    int b = (int)(int8_t)(v & 0xff);
                    dig[e][d] = b & 0xff;
                    v = (v - b) >> 8;                        // exact
                }
            }
#pragma unroll
            for (int d = 0; d < 4; ++d) {
                uint32_t wrd = (uint32_t)dig[0][d] | ((uint32_t)dig[1][d] << 8)
                             | ((uint32_t)dig[2][d] << 16) | ((uint32_t)dig[3][d] << 24);
                *(uint32_t*)(tile + i * 4096 + d * 1024 + ldsQ) = wrd;
            }
        }
        __syncthreads();
        {   // tile is byte-identical to global span [mb32<<19 | kw<<14 .. +16KB)
            const int4* s = (const int4*)tile;
            int4* dst = (int4*)(dstBase + ((size_t)kw << 14));
#pragma unroll
            for (int q = 0; q < 4; ++q) dst[t + 256 * q] = s[t + 256 * q];
        }
        __syncthreads();
    }
}

// ---------------- fallback: R1 planar in-place pack ------------------------
__global__ void pack_x_kernel(float* __restrict__ x) {
    const int b = blockIdx.x, t = threadIdx.x;
    float* row = x + (size_t)b * DIM;
    float f[16];
#pragma unroll
    for (int i = 0; i < 4; ++i) {
        float4 v = ((const float4*)(row + t * 16))[i];
        f[i*4+0] = v.x; f[i*4+1] = v.y; f[i*4+2] = v.z; f[i*4+3] = v.w;
    }
    __syncthreads();
    uint32_t wds[4][4];
#pragma unroll
    for (int j = 0; j < 4; ++j) {
#pragma unroll
        for (int d = 0; d < 4; ++d) wds[d][j] = 0u;
#pragma unroll
        for (int i = 0; i < 4; ++i) {
            int v = __float2int_rn(f[j*4+i] * 67108864.0f);
#pragma unroll
            for (int d = 0; d < 4; ++d) {
                int bb = (int)(int8_t)(v & 0xff);
                wds[d][j] |= (uint32_t)(bb & 0xff) << (8 * i);
                v = (v - bb) >> 8;
            }
        }
    }
    int8_t* rowb = (int8_t*)row;
#pragma unroll
    for (int d = 0; d < 4; ++d) {
        int4 o; o.x = (int)wds[d][0]; o.y = (int)wds[d][1];
        o.z = (int)wds[d][2]; o.w = (int)wds[d][3];
        *(int4*)(rowb + d * DIM + t * 16) = o;
    }
}

// ---------------- pack W1 signs into MFMA-fragment-ordered blocks ----------
__global__ void pack_w1_kernel(const float* __restrict__ W1, int8_t* __restrict__ wsB) {
    const int tg = blockIdx.x * 256 + threadIdx.x;
    const int n  = tg >> 8;
    const int k0 = (tg & 255) << 4;
    const float* src = W1 + (size_t)n * DIM + k0;
    uint32_t w[4];
#pragma unroll
    for (int j = 0; j < 4; ++j) {
        float4 v = ((const float4*)src)[j];
        uint32_t b0 = (v.x >= 0.f) ? 0x01u : 0xFFu;
        uint32_t b1 = (v.y >= 0.f) ? 0x01u : 0xFFu;
        uint32_t b2 = (v.z >= 0.f) ? 0x01u : 0xFFu;
        uint32_t b3 = (v.w >= 0.f) ? 0x01u : 0xFFu;
        w[j] = b0 | (b1 << 8) | (b2 << 16) | (b3 << 24);
    }
    const int nb = n >> 7, kt = k0 >> 6;
    const int nsub = (n >> 5) & 3, ks = (k0 >> 5) & 1;
    const int L = (n & 31) | (((k0 >> 4) & 1) << 5);
    const size_t off = ((size_t)(nb * 64 + kt) << 13) + (nsub << 11) + (ks << 10) + (L << 4);
    int4 o; o.x = (int)w[0]; o.y = (int)w[1]; o.z = (int)w[2]; o.w = (int)w[3];
    *(int4*)(wsB + off) = o;
}

__global__ void pack_w2_kernel(const float* __restrict__ W2, int8_t* __restrict__ w2s) {
    const int j = blockIdx.x * 256 + threadIdx.x;
    if (j < DIM) w2s[j] = (W2[j] >= 0.f) ? (int8_t)1 : (int8_t)-1;
}

// ---------------- R7 GEMM: 1024 threads, MT=128 NT=256, all-dma16 ----------
// LDS stage buffer (48 KB): A region [0,32K): chunk (mpos<<3|ks<<2|d)<<10;
// B region [32K,48K): chunk (ng2<<3|nsub<<1|ks)<<10. Wave w stages A chunks
// 2w,2w+1 and B chunk w (3 dma16/stage). Steady-state wait = vmcnt(3).
#define STGB 49152

#define PIPE_BARRIER(N) do {                                               \
    __builtin_amdgcn_sched_barrier(0);                                     \
    asm volatile("s_waitcnt vmcnt(" #N ") lgkmcnt(0)" ::: "memory");       \
    __builtin_amdgcn_s_barrier();                                          \
    __builtin_amdgcn_sched_barrier(0);                                     \
} while (0)

#define ISSUE_STAGE(kt_, ib) do {                                          \
    const size_t _ko = (size_t)(kt_) << 13;                                \
    int8_t* _sb = stg + (ib) * STGB;                                       \
    dma16(gA0 + _ko, _sb + aD0);                                           \
    dma16(gA0 + _ko + 1024, _sb + aD0 + 1024);                             \
    dma16(gB  + _ko, _sb + bD);                                            \
} while (0)

#define MFMA_STAGE(cb) do {                                                \
    const int8_t* _ab = stg + (cb) * STGB + (wy << 13) + (lane << 4);      \
    const int8_t* _bb = stg + (cb) * STGB + 32768 + (wx << 12) + (lane << 4); \
    v4i _af[2][4], _bf[2][2];                                              \
    _Pragma("unroll") for (int _s = 0; _s < 2; ++_s) {                     \
        _Pragma("unroll") for (int _d = 0; _d < 4; ++_d)                   \
            _af[_s][_d] = *(const v4i*)(_ab + (_s << 12) + (_d << 10));    \
        _Pragma("unroll") for (int _n = 0; _n < 2; ++_n)                   \
            _bf[_s][_n] = *(const v4i*)(_bb + (_n << 11) + (_s << 10));    \
    }                                                                      \
    __builtin_amdgcn_s_setprio(1);                                         \
    _Pragma("unroll") for (int _s = 0; _s < 2; ++_s)                       \
    _Pragma("unroll") for (int _n = 0; _n < 2; ++_n)                       \
    _Pragma("unroll") for (int _d = 0; _d < 4; ++_d)                       \
        acc[_n][_d] = __builtin_amdgcn_mfma_i32_32x32x32_i8(               \
            _af[_s][_d], _bf[_s][_n], acc[_n][_d], 0, 0, 0);               \
    __builtin_amdgcn_s_setprio(0);                                         \
} while (0)

#define STEP(kt_, cb, ib) do {                                             \
    PIPE_BARRIER(3);                                                       \
    ISSUE_STAGE((kt_) + 2, ib);                                            \
    __builtin_amdgcn_sched_barrier(0);                                     \
    MFMA_STAGE(cb);                                                        \
} while (0)

__launch_bounds__(1024, 4)
__global__ void gemm_direct_kernel(const int8_t* __restrict__ wsA,
                                   const int8_t* __restrict__ wsB,
                                   const int8_t* __restrict__ w2s,
                                   int* __restrict__ logit) {
    __shared__ __align__(16) int8_t stg[3 * STGB];   // 144 KB, 1 block/CU

    // bijective XCD swizzle: 2048 blocks, 8 XCDs -> XCD x owns newbid in
    // [x*256,(x+1)*256) = 16 contiguous mb rows (all nb2) -> A L2-resident.
    const int newbid = (blockIdx.x & 7) * 256 + (blockIdx.x >> 3);
    const int nb2 = newbid & 15, mb = newbid >> 4;   // nb2 fastest: share A
    const int t = threadIdx.x, lane = t & 63, w = t >> 6;   // w in 0..15
    const int wy = w >> 2, wx = w & 3;        // wave tile: 32(m) x 64(n)

    v16i acc[2][4];
#pragma unroll
    for (int n = 0; n < 2; ++n)
#pragma unroll
        for (int d = 0; d < 4; ++d)
#pragma unroll
            for (int i = 0; i < 16; ++i) acc[n][d][i] = 0;

    // A staging: wave w loads chunks c=2w,2w+1 -> (mpos=w>>2, ks=(w>>1)&1,
    // d=(w&1)*2 +{0,1}); global stream is fragment-ordered, stride 8KB/stage.
    const int mposA = w >> 2, ksA = (w >> 1) & 1, dA = (w & 1) * 2;
    const int8_t* gA0 = wsA + ((size_t)(mb * 4 + mposA) << 19)
                            + ((size_t)ksA << 12) + ((size_t)dA << 10) + (lane << 4);
    const int aD0 = w << 11;
    // B staging: wave w loads chunk (ng2=w>>3, nsub=(w>>1)&3, ks=w&1).
    const int8_t* gB = wsB + ((size_t)((nb2 * 2 + (w >> 3)) * 64) << 13)
                           + ((size_t)((w >> 1) & 3) << 11)
                           + ((size_t)(w & 1) << 10) + (lane << 4);
    const int bD = 32768 + (w << 10);

    // prologue: stages 0,1 in flight (3 ops each, per wave).
    ISSUE_STAGE(0, 0);
    ISSUE_STAGE(1, 1);

    // 64 stages; consume kt%3, issue (kt+2)%3. Reuse distance 1 is safe:
    // lgkmcnt(0) in PIPE_BARRIER drains each wave's ds_reads of stage kt-1
    // before any wave passes the barrier; the overwrite DMA issues after.
#pragma unroll 1
    for (int kt = 0; kt < 60; kt += 3) {
        STEP(kt + 0, 0, 2);
        STEP(kt + 1, 1, 0);
        STEP(kt + 2, 2, 1);
    }
    STEP(60, 0, 2);   // issues stage 62 -> buf 2
    STEP(61, 1, 0);   // issues stage 63 -> buf 0
    PIPE_BARRIER(3);  // stage 62 landed (63's 3 ops outstanding)
    MFMA_STAGE(2);
    PIPE_BARRIER(0);  // final drain: stage 63 landed
    MFMA_STAGE(0);

    // epilogue: recombine digits -> exact sign -> *sign(W2) -> row sums -> atomic
    const int half = lane >> 5, col = lane & 31;
    int psum[16];
#pragma unroll
    for (int r = 0; r < 16; ++r) psum[r] = 0;
#pragma unroll
    for (int n = 0; n < 2; ++n) {
        const int j = nb2 * NT + wx * 64 + n * 32 + col;
        const int w2v = (int)w2s[j];
#pragma unroll
        for (int r = 0; r < 16; ++r) {
            long long h = (long long)acc[n][0][r]
                        + ((long long)acc[n][1][r] << 8)
                        + ((long long)acc[n][2][r] << 16)
                        + ((long long)acc[n][3][r] << 24);
            psum[r] += (h >= 0) ? w2v : -w2v;
        }
    }
#pragma unroll
    for (int r = 0; r < 16; ++r) {
#pragma unroll
        for (int m = 1; m <= 16; m <<= 1)
            psum[r] += __shfl_xor(psum[r], m, 64);
    }
    if (col == 0) {
        const int rowBase = mb * MT + wy * 32 + 4 * half;
#pragma unroll
        for (int r = 0; r < 16; ++r)
            atomicAdd(logit + rowBase + (r & 3) + 8 * (r >> 2), psum[r]);
    }
}

// ---------------- fallback: R1 GEMM (A planar through LDS) -----------------
__launch_bounds__(256, 2)
__global__ void gemm_kernel(const int8_t* __restrict__ xq,
                            const int8_t* __restrict__ wsB,
                            const int8_t* __restrict__ w2s,
                            int* __restrict__ logit) {
    __shared__ __align__(16) int8_t aT[4 * 64 * KT];
    __shared__ __align__(16) int8_t bT[128 * KT];

    const int bid = blockIdx.x;
    const int nb = bid & 31, mb = bid >> 5;
    const int t = threadIdx.x, lane = t & 63, w = t >> 6;
    const int wy = w >> 1, wx = w & 1;

    v16i acc[2][4];
#pragma unroll
    for (int n = 0; n < 2; ++n)
#pragma unroll
        for (int d = 0; d < 4; ++d)
#pragma unroll
            for (int i = 0; i < 16; ++i) acc[n][d][i] = 0;

    const int8_t* aSrc = xq + (size_t)(mb * 64 + lane) * (4 * DIM) + w * DIM;
    const int8_t* bSrc = wsB + ((size_t)(nb * 64) << 13) + t * 32;
    const int aDst = w * (64 * KT) + ((lane >> 5) << 11) + ((lane & 31) << 4);

    for (int kt = 0; kt < DIM / KT; ++kt) {
#pragma unroll
        for (int k16 = 0; k16 < 4; ++k16) {
            v4i v = *(const v4i*)(aSrc + kt * KT + k16 * 16);
            *(v4i*)(aT + aDst + ((k16 >> 1) << 10) + ((k16 & 1) << 9)) = v;
        }
        {
            const v4i* s = (const v4i*)(bSrc + ((size_t)kt << 13));
            *(v4i*)(bT + t * 32)      = s[0];
            *(v4i*)(bT + t * 32 + 16) = s[1];
        }
        __syncthreads();
#pragma unroll
        for (int s = 0; s < 2; ++s) {
            v4i af[4], bf[2];
#pragma unroll
            for (int d = 0; d < 4; ++d)
                af[d] = *(const v4i*)(aT + d * (64 * KT) + (wy << 11) + (s << 10) + (lane << 4));
#pragma unroll
            for (int n = 0; n < 2; ++n)
                bf[n] = *(const v4i*)(bT + ((wx * 2 + n) << 11) + (s << 10) + (lane << 4));
#pragma unroll
            for (int n = 0; n < 2; ++n)
#pragma unroll
                for (int d = 0; d < 4; ++d)
                    acc[n][d] = __builtin_amdgcn_mfma_i32_32x32x32_i8(af[d], bf[n], acc[n][d], 0, 0, 0);
        }
        __syncthreads();
    }

    const int half = lane >> 5, col = lane & 31;
    int psum[16];
#pragma unroll
    for (int r = 0; r < 16; ++r) psum[r] = 0;
#pragma unroll
    for (int n = 0; n < 2; ++n) {
        const int j = nb * 128 + wx * 64 + n * 32 + col;
        const int w2v = (int)w2s[j];
#pragma unroll
        for (int r = 0; r < 16; ++r) {
            long long h = (long long)acc[n][0][r]
                        + ((long long)acc[n][1][r] << 8)
                        + ((long long)acc[n][2][r] << 16)
                        + ((long long)acc[n][3][r] << 24);
            psum[r] += (h >= 0) ? w2v : -w2v;
        }
    }
#pragma unroll
    for (int r = 0; r < 16; ++r) {
#pragma unroll
        for (int m = 1; m <= 16; m <<= 1)
            psum[r] += __shfl_xor(psum[r], m, 64);
    }
    if (col == 0) {
        const int rowBase = mb * 64 + wy * 32 + 4 * half;
#pragma unroll
        for (int r = 0; r < 16; ++r)
            atomicAdd(logit + rowBase + (r & 3) + 8 * (r >> 2), psum[r]);
    }
}

// ---------------- finalize: sigmoid + threshold ----------------------------
__global__ void finalize_kernel(const int* __restrict__ logit, float* __restrict__ out) {
    const int b = blockIdx.x * 256 + threadIdx.x;
    if (b < B_ROWS) {
        const int l = logit[b];
        out[b]          = 1.f / (1.f + expf(-(float)l));
        out[B_ROWS + b] = (l >= 0) ? 1.f : 0.f;
    }
}

extern "C" void kernel_launch(void* const* d_in, const int* in_sizes, int n_in,
                              void* d_out, int out_size, void* d_ws, size_t ws_size,
                              hipStream_t stream) {
    float*       x   = (float*)d_in[0];
    const float* W1  = (const float*)d_in[1];
    const float* W2  = (const float*)d_in[2];
    float*       out = (float*)d_out;

    int8_t* ws    = (int8_t*)d_ws;
    int*    logit = (int*)(ws + WS_LOGIT);
    int8_t* w2s   = ws + WS_W2S;
    int8_t* wsB   = ws + WS_B;

    hipMemsetAsync(logit, 0, B_ROWS * sizeof(int), stream);
    pack_w1_kernel<<<DIM, 256, 0, stream>>>(W1, wsB);
    pack_w2_kernel<<<16, 256, 0, stream>>>(W2, w2s);

    if (ws_size >= WS_NEEDED) {
        int8_t* wsA = ws + WS_A;
        pack_x_frag_kernel<<<B_ROWS / 32, 256, 0, stream>>>(x, wsA);
        gemm_direct_kernel<<<(B_ROWS / MT) * (DIM / NT), 1024, 0, stream>>>(wsA, wsB, w2s, logit);
    } else {
        pack_x_kernel<<<B_ROWS, 256, 0, stream>>>(x);
        gemm_kernel<<<(B_ROWS / 64) * (DIM / 128), 256, 0, stream>>>((const int8_t*)x, wsB, w2s, logit);
    }
    finalize_kernel<<<B_ROWS / 256, 256, 0, stream>>>(logit, out);
}

// Round 5
// 1564.290 us; speedup vs baseline: 13.7594x; 13.7594x over previous
//
#include <hip/hip_runtime.h>
#include <stdint.h>

// Binary-weight MLP forward, exact int8 digit-plane formulation.
// R8: arithmetic-intensity fix that respects the register file. Evidence:
// all high-perf MI355X GEMMs (m97 912TF, 8-phase 1728TF, hipBLASLt 2026TF)
// sustain ~22-26 B/cyc/CU of operand traffic — same as our measured 20-25.
// R4 required 42 B/cyc (51% util); R7's 16-wave fix spilled (128-reg cap).
// R8: MT=64 x NT=256, 512 threads (8 waves, 1 block/CU), wave-tile 32x64
// unchanged (128 AGPR acc, ~180 regs vs 256 budget at the mandatory
// 2 waves/SIMD -> no spill possible). Required rate = 896(4/NT+1/MT) =
// 28 B/cyc. All operands via global_load_lds (no duplication), 3-deep
// buffers (96 KB LDS), 4 dma16/wave/stage, steady s_waitcnt vmcnt(4),
// one barrier per stage. Bijective XCD swizzle (4096 = 8*512).

typedef int v4i  __attribute__((ext_vector_type(4)));
typedef int v16i __attribute__((ext_vector_type(16)));

#define B_ROWS   16384
#define DIM      4096
#define MT       64      // block m-tile
#define NT       256     // block n-tile (R8)
#define KT       64      // k-tile (pipeline stage)

#define WS_LOGIT  0
#define WS_W2S    65536
#define WS_B      69632
#define WS_A      (69632 + 16777216)
#define WS_NEEDED ((size_t)WS_A + 268435456ULL)

__device__ __forceinline__ void dma16(const void* g, void* l) {
    __builtin_amdgcn_global_load_lds(
        (const __attribute__((address_space(1))) void*)g,
        (__attribute__((address_space(3))) void*)l, 16, 0, 0);
}

// ---------------- pack x -> fragment-ordered digit planes in wsA -----------
// Global layout: offA(m,k,d) = (m>>5)<<19 | (k>>5)<<12 | d<<10 | L<<4 | (k&15)
//   with L = ((k>>4)&1)*32 + (m&31)  (== MFMA A-operand lane index).
__global__ void pack_x_frag_kernel(const float* __restrict__ x, int8_t* __restrict__ wsA) {
    __shared__ __align__(16) int8_t tile[16384];
    const int mb32 = blockIdx.x, t = threadIdx.x;
    const int r = t >> 3;          // row within 32-row group
    const int c = t & 7;           // float4-column subgroup
    const int kh = (c >> 2) & 1;   // (k>>4)&1 for this thread's elements
    const int L = kh * 32 + r;
    const int ldsQ = L * 16 + (c & 3) * 4;   // + i*4096 + d*1024
    const float* srcRow = x + ((size_t)(mb32 * 32 + r) << 12);
    int8_t* dstBase = wsA + ((size_t)mb32 << 19);

    for (int kw = 0; kw < 32; ++kw) {
#pragma unroll
        for (int i = 0; i < 4; ++i) {
            const int j = c + 8 * i;                       // float4 index in window
            float4 f = ((const float4*)(srcRow + (kw << 7)))[j];
            float fv[4] = {f.x, f.y, f.z, f.w};
            int dig[4][4];                                  // [elem][digit]
#pragma unroll
            for (int e = 0; e < 4; ++e) {
                int v = __float2int_rn(fv[e] * 67108864.0f); // * 2^26, exact
#pragma unroll
                for (int d = 0; d < 4; ++d) {
                    int b = (int)(int8_t)(v & 0xff);
                    dig[e][d] = b & 0xff;
                    v = (v - b) >> 8;                        // exact
                }
            }
#pragma unroll
            for (int d = 0; d < 4; ++d) {
                uint32_t wrd = (uint32_t)dig[0][d] | ((uint32_t)dig[1][d] << 8)
                             | ((uint32_t)dig[2][d] << 16) | ((uint32_t)dig[3][d] << 24);
                *(uint32_t*)(tile + i * 4096 + d * 1024 + ldsQ) = wrd;
            }
        }
        __syncthreads();
        {   // tile is byte-identical to global span [mb32<<19 | kw<<14 .. +16KB)
            const int4* s = (const int4*)tile;
            int4* dst = (int4*)(dstBase + ((size_t)kw << 14));
#pragma unroll
            for (int q = 0; q < 4; ++q) dst[t + 256 * q] = s[t + 256 * q];
        }
        __syncthreads();
    }
}

// ---------------- fallback: R1 planar in-place pack ------------------------
__global__ void pack_x_kernel(float* __restrict__ x) {
    const int b = blockIdx.x, t = threadIdx.x;
    float* row = x + (size_t)b * DIM;
    float f[16];
#pragma unroll
    for (int i = 0; i < 4; ++i) {
        float4 v = ((const float4*)(row + t * 16))[i];
        f[i*4+0] = v.x; f[i*4+1] = v.y; f[i*4+2] = v.z; f[i*4+3] = v.w;
    }
    __syncthreads();
    uint32_t wds[4][4];
#pragma unroll
    for (int j = 0; j < 4; ++j) {
#pragma unroll
        for (int d = 0; d < 4; ++d) wds[d][j] = 0u;
#pragma unroll
        for (int i = 0; i < 4; ++i) {
            int v = __float2int_rn(f[j*4+i] * 67108864.0f);
#pragma unroll
            for (int d = 0; d < 4; ++d) {
                int bb = (int)(int8_t)(v & 0xff);
                wds[d][j] |= (uint32_t)(bb & 0xff) << (8 * i);
                v = (v - bb) >> 8;
            }
        }
    }
    int8_t* rowb = (int8_t*)row;
#pragma unroll
    for (int d = 0; d < 4; ++d) {
        int4 o; o.x = (int)wds[d][0]; o.y = (int)wds[d][1];
        o.z = (int)wds[d][2]; o.w = (int)wds[d][3];
        *(int4*)(rowb + d * DIM + t * 16) = o;
    }
}

// ---------------- pack W1 signs into MFMA-fragment-ordered blocks ----------
__global__ void pack_w1_kernel(const float* __restrict__ W1, int8_t* __restrict__ wsB) {
    const int tg = blockIdx.x * 256 + threadIdx.x;
    const int n  = tg >> 8;
    const int k0 = (tg & 255) << 4;
    const float* src = W1 + (size_t)n * DIM + k0;
    uint32_t w[4];
#pragma unroll
    for (int j = 0; j < 4; ++j) {
        float4 v = ((const float4*)src)[j];
        uint32_t b0 = (v.x >= 0.f) ? 0x01u : 0xFFu;
        uint32_t b1 = (v.y >= 0.f) ? 0x01u : 0xFFu;
        uint32_t b2 = (v.z >= 0.f) ? 0x01u : 0xFFu;
        uint32_t b3 = (v.w >= 0.f) ? 0x01u : 0xFFu;
        w[j] = b0 | (b1 << 8) | (b2 << 16) | (b3 << 24);
    }
    const int nb = n >> 7, kt = k0 >> 6;
    const int nsub = (n >> 5) & 3, ks = (k0 >> 5) & 1;
    const int L = (n & 31) | (((k0 >> 4) & 1) << 5);
    const size_t off = ((size_t)(nb * 64 + kt) << 13) + (nsub << 11) + (ks << 10) + (L << 4);
    int4 o; o.x = (int)w[0]; o.y = (int)w[1]; o.z = (int)w[2]; o.w = (int)w[3];
    *(int4*)(wsB + off) = o;
}

__global__ void pack_w2_kernel(const float* __restrict__ W2, int8_t* __restrict__ w2s) {
    const int j = blockIdx.x * 256 + threadIdx.x;
    if (j < DIM) w2s[j] = (W2[j] >= 0.f) ? (int8_t)1 : (int8_t)-1;
}

// ---------------- R8 GEMM: 512 thr, MT=64 NT=256, all-dma16 ----------------
// LDS stage (32 KB): A [0,16K): chunk (mg<<3|ks<<2|d)<<10; B [16K,32K):
// chunk (g<<3|nsub<<1|ks)<<10. Wave w stages A chunks 2w,2w+1 and B chunks
// 2w,2w+1 (4 dma16/stage). Steady-state wait = vmcnt(4) (1 stage in flight
// after the wait; issue depth is 2 stages ahead).
#define STGB 32768

#define PIPE_BARRIER(N) do {                                               \
    __builtin_amdgcn_sched_barrier(0);                                     \
    asm volatile("s_waitcnt vmcnt(" #N ") lgkmcnt(0)" ::: "memory");       \
    __builtin_amdgcn_s_barrier();                                          \
    __builtin_amdgcn_sched_barrier(0);                                     \
} while (0)

#define ISSUE_STAGE(kt_, ib) do {                                          \
    const size_t _ko = (size_t)(kt_) << 13;                                \
    int8_t* _sb = stg + (ib) * STGB;                                       \
    dma16(gA0 + _ko,        _sb + (w << 11));                              \
    dma16(gA0 + _ko + 1024, _sb + (w << 11) + 1024);                       \
    dma16(gB0 + _ko,        _sb + 16384 + (w << 11));                      \
    dma16(gB0 + _ko + 1024, _sb + 16384 + (w << 11) + 1024);               \
} while (0)

#define MFMA_STAGE(cb) do {                                                \
    const int8_t* _ab = stg + (cb) * STGB + (wy << 13) + (lane << 4);      \
    const int8_t* _bb = stg + (cb) * STGB + 16384 + (wx << 12) + (lane << 4); \
    _Pragma("unroll") for (int _s = 0; _s < 2; ++_s) {                     \
        v4i _af[4], _bf[2];                                                \
        _Pragma("unroll") for (int _d = 0; _d < 4; ++_d)                   \
            _af[_d] = *(const v4i*)(_ab + (_s << 12) + (_d << 10));        \
        _Pragma("unroll") for (int _n = 0; _n < 2; ++_n)                   \
            _bf[_n] = *(const v4i*)(_bb + (_n << 11) + (_s << 10));        \
        __builtin_amdgcn_s_setprio(1);                                     \
        _Pragma("unroll") for (int _n = 0; _n < 2; ++_n)                   \
        _Pragma("unroll") for (int _d = 0; _d < 4; ++_d)                   \
            acc[_n][_d] = __builtin_amdgcn_mfma_i32_32x32x32_i8(           \
                _af[_d], _bf[_n], acc[_n][_d], 0, 0, 0);                   \
        __builtin_amdgcn_s_setprio(0);                                     \
    }                                                                      \
} while (0)

#define STEP(kt_, cb, ib) do {                                             \
    PIPE_BARRIER(4);                                                       \
    ISSUE_STAGE((kt_) + 2, ib);                                            \
    __builtin_amdgcn_sched_barrier(0);                                     \
    MFMA_STAGE(cb);                                                        \
} while (0)

__launch_bounds__(512, 2)
__global__ void gemm_direct_kernel(const int8_t* __restrict__ wsA,
                                   const int8_t* __restrict__ wsB,
                                   const int8_t* __restrict__ w2s,
                                   int* __restrict__ logit) {
    __shared__ __align__(16) int8_t stg[3 * STGB];   // 96 KB, 1 block/CU

    // bijective XCD swizzle: 4096 blocks = 8 XCDs x 512. XCD x owns 32 mb
    // groups x 16 nb2; nb2 fastest -> 1 MB A-window L2-resident per sweep.
    const int newbid = (blockIdx.x & 7) * 512 + (blockIdx.x >> 3);
    const int nb2 = newbid & 15, mb = newbid >> 4;
    const int t = threadIdx.x, lane = t & 63, w = t >> 6;   // w in 0..7
    const int wy = w >> 2, wx = w & 3;        // wave tile: 32(m) x 64(n)

    v16i acc[2][4];
#pragma unroll
    for (int n = 0; n < 2; ++n)
#pragma unroll
        for (int d = 0; d < 4; ++d)
#pragma unroll
            for (int i = 0; i < 16; ++i) acc[n][d][i] = 0;

    // A staging: wave w loads chunks 2w,2w+1 -> (mg=w>>2, ks=(w>>1)&1,
    // d = (w&1)*2 + {0,1}); global stream fragment-ordered, 8 KB/stage/group.
    const int8_t* gA0 = wsA + ((size_t)(mb * 2 + (w >> 2)) << 19)
                            + ((size_t)((w >> 1) & 1) << 12)
                            + ((size_t)(w & 1) << 11) + (lane << 4);
    // B staging: wave w loads chunks 2w,2w+1 -> piece g=w>>2 (128-col group
    // 2*nb2+g), nsub=w&3, ks={0,1}.
    const int8_t* gB0 = wsB + ((size_t)((nb2 * 2 + (w >> 2)) * 64) << 13)
                            + ((size_t)(w & 3) << 11) + (lane << 4);

    // prologue: stages 0,1 in flight (4 ops each, per wave).
    ISSUE_STAGE(0, 0);
    ISSUE_STAGE(1, 1);

    // 64 stages; consume kt%3, issue (kt+2)%3. Reuse distance 1 is safe:
    // lgkmcnt(0) in PIPE_BARRIER drains each wave's ds_reads of the stage
    // being overwritten before the barrier; the DMA issues after it.
#pragma unroll 1
    for (int kt = 0; kt < 60; kt += 3) {
        STEP(kt + 0, 0, 2);
        STEP(kt + 1, 1, 0);
        STEP(kt + 2, 2, 1);
    }
    STEP(60, 0, 2);   // issues stage 62 -> buf 2
    STEP(61, 1, 0);   // issues stage 63 -> buf 0
    PIPE_BARRIER(4);  // stage 62 landed (63's 4 ops outstanding)
    MFMA_STAGE(2);
    PIPE_BARRIER(0);  // final drain: stage 63 landed
    MFMA_STAGE(0);

    // epilogue: recombine digits -> exact sign -> *sign(W2) -> row sums -> atomic
    const int half = lane >> 5, col = lane & 31;
    int psum[16];
#pragma unroll
    for (int r = 0; r < 16; ++r) psum[r] = 0;
#pragma unroll
    for (int n = 0; n < 2; ++n) {
        const int j = nb2 * NT + wx * 64 + n * 32 + col;
        const int w2v = (int)w2s[j];
#pragma unroll
        for (int r = 0; r < 16; ++r) {
            long long h = (long long)acc[n][0][r]
                        + ((long long)acc[n][1][r] << 8)
                        + ((long long)acc[n][2][r] << 16)
                        + ((long long)acc[n][3][r] << 24);
            psum[r] += (h >= 0) ? w2v : -w2v;
        }
    }
#pragma unroll
    for (int r = 0; r < 16; ++r) {
#pragma unroll
        for (int m = 1; m <= 16; m <<= 1)
            psum[r] += __shfl_xor(psum[r], m, 64);
    }
    if (col == 0) {
        const int rowBase = mb * MT + wy * 32 + 4 * half;
#pragma unroll
        for (int r = 0; r < 16; ++r)
            atomicAdd(logit + rowBase + (r & 3) + 8 * (r >> 2), psum[r]);
    }
}

// ---------------- fallback: R1 GEMM (A planar through LDS) -----------------
__launch_bounds__(256, 2)
__global__ void gemm_kernel(const int8_t* __restrict__ xq,
                            const int8_t* __restrict__ wsB,
                            const int8_t* __restrict__ w2s,
                            int* __restrict__ logit) {
    __shared__ __align__(16) int8_t aT[4 * 64 * KT];
    __shared__ __align__(16) int8_t bT[128 * KT];

    const int bid = blockIdx.x;
    const int nb = bid & 31, mb = bid >> 5;
    const int t = threadIdx.x, lane = t & 63, w = t >> 6;
    const int wy = w >> 1, wx = w & 1;

    v16i acc[2][4];
#pragma unroll
    for (int n = 0; n < 2; ++n)
#pragma unroll
        for (int d = 0; d < 4; ++d)
#pragma unroll
            for (int i = 0; i < 16; ++i) acc[n][d][i] = 0;

    const int8_t* aSrc = xq + (size_t)(mb * 64 + lane) * (4 * DIM) + w * DIM;
    const int8_t* bSrc = wsB + ((size_t)(nb * 64) << 13) + t * 32;
    const int aDst = w * (64 * KT) + ((lane >> 5) << 11) + ((lane & 31) << 4);

    for (int kt = 0; kt < DIM / KT; ++kt) {
#pragma unroll
        for (int k16 = 0; k16 < 4; ++k16) {
            v4i v = *(const v4i*)(aSrc + kt * KT + k16 * 16);
            *(v4i*)(aT + aDst + ((k16 >> 1) << 10) + ((k16 & 1) << 9)) = v;
        }
        {
            const v4i* s = (const v4i*)(bSrc + ((size_t)kt << 13));
            *(v4i*)(bT + t * 32)      = s[0];
            *(v4i*)(bT + t * 32 + 16) = s[1];
        }
        __syncthreads();
#pragma unroll
        for (int s = 0; s < 2; ++s) {
            v4i af[4], bf[2];
#pragma unroll
            for (int d = 0; d < 4; ++d)
                af[d] = *(const v4i*)(aT + d * (64 * KT) + (wy << 11) + (s << 10) + (lane << 4));
#pragma unroll
            for (int n = 0; n < 2; ++n)
                bf[n] = *(const v4i*)(bT + ((wx * 2 + n) << 11) + (s << 10) + (lane << 4));
#pragma unroll
            for (int n = 0; n < 2; ++n)
#pragma unroll
                for (int d = 0; d < 4; ++d)
                    acc[n][d] = __builtin_amdgcn_mfma_i32_32x32x32_i8(af[d], bf[n], acc[n][d], 0, 0, 0);
        }
        __syncthreads();
    }

    const int half = lane >> 5, col = lane & 31;
    int psum[16];
#pragma unroll
    for (int r = 0; r < 16; ++r) psum[r] = 0;
#pragma unroll
    for (int n = 0; n < 2; ++n) {
        const int j = nb * 128 + wx * 64 + n * 32 + col;
        const int w2v = (int)w2s[j];
#pragma unroll
        for (int r = 0; r < 16; ++r) {
            long long h = (long long)acc[n][0][r]
                        + ((long long)acc[n][1][r] << 8)
                        + ((long long)acc[n][2][r] << 16)
                        + ((long long)acc[n][3][r] << 24);
            psum[r] += (h >= 0) ? w2v : -w2v;
        }
    }
#pragma unroll
    for (int r = 0; r < 16; ++r) {
#pragma unroll
        for (int m = 1; m <= 16; m <<= 1)
            psum[r] += __shfl_xor(psum[r], m, 64);
    }
    if (col == 0) {
        const int rowBase = mb * 64 + wy * 32 + 4 * half;
#pragma unroll
        for (int r = 0; r < 16; ++r)
            atomicAdd(logit + rowBase + (r & 3) + 8 * (r >> 2), psum[r]);
    }
}

// ---------------- finalize: sigmoid + threshold ----------------------------
__global__ void finalize_kernel(const int* __restrict__ logit, float* __restrict__ out) {
    const int b = blockIdx.x * 256 + threadIdx.x;
    if (b < B_ROWS) {
        const int l = logit[b];
        out[b]          = 1.f / (1.f + expf(-(float)l));
        out[B_ROWS + b] = (l >= 0) ? 1.f : 0.f;
    }
}

extern "C" void kernel_launch(void* const* d_in, const int* in_sizes, int n_in,
                              void* d_out, int out_size, void* d_ws, size_t ws_size,
                              hipStream_t stream) {
    float*       x   = (float*)d_in[0];
    const float* W1  = (const float*)d_in[1];
    const float* W2  = (const float*)d_in[2];
    float*       out = (float*)d_out;

    int8_t* ws    = (int8_t*)d_ws;
    int*    logit = (int*)(ws + WS_LOGIT);
    int8_t* w2s   = ws + WS_W2S;
    int8_t* wsB   = ws + WS_B;

    hipMemsetAsync(logit, 0, B_ROWS * sizeof(int), stream);
    pack_w1_kernel<<<DIM, 256, 0, stream>>>(W1, wsB);
    pack_w2_kernel<<<16, 256, 0, stream>>>(W2, w2s);

    if (ws_size >= WS_NEEDED) {
        int8_t* wsA = ws + WS_A;
        pack_x_frag_kernel<<<B_ROWS / 32, 256, 0, stream>>>(x, wsA);
        gemm_direct_kernel<<<(B_ROWS / MT) * (DIM / NT), 512, 0, stream>>>(wsA, wsB, w2s, logit);
    } else {
        pack_x_kernel<<<B_ROWS, 256, 0, stream>>>(x);
        gemm_kernel<<<(B_ROWS / 64) * (DIM / 128), 256, 0, stream>>>((const int8_t*)x, wsB, w2s, logit);
    }
    finalize_kernel<<<B_ROWS / 256, 256, 0, stream>>>(logit, out);
}